// Round 5
// baseline (2085.523 us; speedup 1.0000x reference)
//
#include <hip/hip_runtime.h>

#define NSTEPS 8
#define DT (1.0f / NSTEPS)

typedef __bf16 bfv8 __attribute__((ext_vector_type(8)));
typedef float f32x4 __attribute__((ext_vector_type(4)));

__device__ __forceinline__ float fast_tanh(float x) {
  float e = __expf(2.f * x);
  return 1.f - 2.f * __builtin_amdgcn_rcpf(e + 1.f);
}

__device__ __forceinline__ f32x4 splat4(float v) {
  f32x4 r; r[0] = v; r[1] = v; r[2] = v; r[3] = v; return r;
}

// ---------------------------------------------------------------------------
// Packed weight layouts (bf16), fragment-major for coalesced B-loads:
//  W1P[kq][512][8]  kq<8  : W1P[kq*4096+col*8+e] = W1[(kq*8+e)*512+col]
//  W2P[kc][512][8]  kc<64 : = W2[(kc*8+e)*512+col]
//  GtP[kc][512][8]  kc<64 : = G[j=col, k=kc*8+e],  G[j,k]=W2[j,k]*sum_i W1[i,j]W3[k,i]
//  W3P[kc][64][8]   kc<64 : = W3[(kc*8+e)*64+m]
// ---------------------------------------------------------------------------
__global__ __launch_bounds__(256) void pre_kernel(
    const float* __restrict__ W1, const float* __restrict__ W2,
    const float* __restrict__ W3, __bf16* __restrict__ W1P,
    __bf16* __restrict__ W2P, __bf16* __restrict__ GtP,
    __bf16* __restrict__ W3P) {
  int t = blockIdx.x * 256 + threadIdx.x;  // 73728 frags total
  if (t < 4096) {
    int kq = t >> 9, col = t & 511;
    bfv8 o;
#pragma unroll
    for (int e = 0; e < 8; ++e) o[e] = (__bf16)W1[(kq * 8 + e) * 512 + col];
    *(bfv8*)(W1P + t * 8) = o;
  } else if (t < 36864) {
    int g = t - 4096;
    int kc = g >> 9, col = g & 511;
    bfv8 o;
#pragma unroll
    for (int e = 0; e < 8; ++e) o[e] = (__bf16)W2[(kc * 8 + e) * 512 + col];
    *(bfv8*)(W2P + g * 8) = o;
  } else if (t < 69632) {
    int g = t - 36864;
    int kc = g >> 9, j = g & 511;
    float w1c[64];
#pragma unroll
    for (int m = 0; m < 64; ++m) w1c[m] = W1[m * 512 + j];
    bfv8 o;
#pragma unroll
    for (int e = 0; e < 8; ++e) {
      int k = kc * 8 + e;
      float s = 0.f;
#pragma unroll
      for (int m = 0; m < 64; ++m) s = fmaf(w1c[m], W3[k * 64 + m], s);
      o[e] = (__bf16)(s * W2[j * 512 + k]);
    }
    *(bfv8*)(GtP + g * 8) = o;
  } else if (t < 73728) {
    int g = t - 69632;
    int kc = g >> 6, m = g & 63;
    bfv8 o;
#pragma unroll
    for (int e = 0; e < 8; ++e) o[e] = (__bf16)W3[(kc * 8 + e) * 64 + m];
    *(bfv8*)(W3P + g * 8) = o;
  }
}

// ---------------------------------------------------------------------------
// Persistent integrator: 32 blocks x 16 rows, 8 waves, 256-VGPR budget.
// MFMA 16x16x32 bf16 (m89 mapping): A row=lane&15,k=(lane>>4)*8+i;
// B col=lane&15,same k; D col=lane&15,row=(lane>>4)*4+reg.
// Per eval: A[combine(reg)+L1] bar B[L2] bar C[TR(waves0-6 + w7 one) | L3(w7)] bar
// ---------------------------------------------------------------------------
__global__ __launch_bounds__(512, 1) void cnf_kernel(
    const float* __restrict__ x, const float* __restrict__ W1,
    const float* __restrict__ b1, const float* __restrict__ b2,
    const float* __restrict__ b3, const __bf16* __restrict__ W1P,
    const __bf16* __restrict__ W2P, const __bf16* __restrict__ GtP,
    const __bf16* __restrict__ W3P, float* __restrict__ out) {
  __shared__ __bf16 h1s[16 * 512];  // row-major, byte ^= (row&7)<<4 swizzle
  __shared__ __bf16 h2s[16 * 512];
  __shared__ __bf16 vs[16 * 512];
  __shared__ float kcur[16 * 64];
  __shared__ float trbuf[16];

  const int tid = threadIdx.x;
  const int lane = tid & 63;
  const int w = tid >> 6;
  const int lr = lane & 15;
  const int lq = lane >> 4;
  const int rowbase = blockIdx.x * 16;
  const char* h1c = (const char*)h1s;
  const char* h2c = (const char*)h2s;
  const char* vsc = (const char*)vs;

  // hoisted per-lane constants
  float b1c[4], w1tc[4], b2c[4], b3c[4];
#pragma unroll
  for (int n = 0; n < 4; ++n) {
    const int col = w * 64 + n * 16 + lr;
    b1c[n] = b1[col];
    w1tc[n] = W1[64 * 512 + col];
    b2c[n] = b2[col];
    b3c[n] = b3[n * 16 + lr];
  }

  // RK4 state in registers (replicated per wave): row lr, k=lq*8+e (+32)
  float xb0[8], xb1[8], ka0[8], ka1[8];
  {
    const float* xr = x + (rowbase + lr) * 64 + lq * 8;
#pragma unroll
    for (int e = 0; e < 8; ++e) {
      xb0[e] = xr[e]; xb1[e] = xr[32 + e]; ka0[e] = 0.f; ka1[e] = 0.f;
    }
  }
  float ldv = 0.f, ldacc = 0.f;  // wave 7 lanes lq==0

#pragma unroll 1
  for (int ev = 0; ev <= 4 * NSTEPS; ++ev) {
    const int g = ev & 3;
    bfv8 a0, a1;
    // ---------------- phase A: combine (registers) ----------------
    if (ev == 0) {
#pragma unroll
      for (int e = 0; e < 8; ++e) { a0[e] = (__bf16)xb0[e]; a1[e] = (__bf16)xb1[e]; }
      if (w == 7 && lq == 0) trbuf[lr] = 0.f;
    } else {
      const int gp = (ev - 1) & 3;
      f32x4 q0 = *(const f32x4*)&kcur[lr * 64 + lq * 8];
      f32x4 q1 = *(const f32x4*)&kcur[lr * 64 + lq * 8 + 4];
      f32x4 q2 = *(const f32x4*)&kcur[lr * 64 + 32 + lq * 8];
      f32x4 q3 = *(const f32x4*)&kcur[lr * 64 + 32 + lq * 8 + 4];
      float kc0[8], kc1[8];
#pragma unroll
      for (int e = 0; e < 4; ++e) { kc0[e] = q0[e]; kc0[e + 4] = q1[e]; kc1[e] = q2[e]; kc1[e + 4] = q3[e]; }
      if (gp < 3) {
        const float wg = (gp == 0) ? 1.f : 2.f;
        const float cn = (gp == 2) ? DT : 0.5f * DT;
#pragma unroll
        for (int e = 0; e < 8; ++e) {
          ka0[e] += wg * kc0[e]; ka1[e] += wg * kc1[e];
          a0[e] = (__bf16)(xb0[e] + cn * kc0[e]);
          a1[e] = (__bf16)(xb1[e] + cn * kc1[e]);
        }
      } else {
#pragma unroll
        for (int e = 0; e < 8; ++e) {
          xb0[e] += (DT / 6.f) * (ka0[e] + kc0[e]);
          xb1[e] += (DT / 6.f) * (ka1[e] + kc1[e]);
          ka0[e] = 0.f; ka1[e] = 0.f;
          a0[e] = (__bf16)xb0[e]; a1[e] = (__bf16)xb1[e];
        }
      }
      if (w == 7 && lq == 0) {
        const float tv = trbuf[lr];
        trbuf[lr] = 0.f;
        if (gp < 3) ldacc += ((gp == 0) ? 1.f : 2.f) * tv;
        else { ldv -= (DT / 6.f) * (ldacc + tv); ldacc = 0.f; }
      }
    }
    if (ev == 4 * NSTEPS) break;

    // ---------------- phase A: L1 ----------------
    const float t = (ev >> 2) * DT + ((g == 0) ? 0.f : (g == 3) ? DT : 0.5f * DT);
#pragma unroll
    for (int n = 0; n < 4; ++n) {
      const int col = w * 64 + n * 16 + lr;
      bfv8 B0 = *(const bfv8*)(W1P + lq * 4096 + col * 8);
      bfv8 B1 = *(const bfv8*)(W1P + (lq + 4) * 4096 + col * 8);
      f32x4 C = splat4(b1c[n] + t * w1tc[n]);
      C = __builtin_amdgcn_mfma_f32_16x16x32_bf16(a0, B0, C, 0, 0, 0);
      C = __builtin_amdgcn_mfma_f32_16x16x32_bf16(a1, B1, C, 0, 0, 0);
#pragma unroll
      for (int r = 0; r < 4; ++r) {
        const int row = lq * 4 + r;
        *(__bf16*)((char*)h1s + row * 1024 + ((col * 2) ^ ((row & 7) << 4))) =
            (__bf16)fast_tanh(C[r]);
      }
    }
    __syncthreads();  // bar1

    // ---------------- phase B: L2 (4 tiles x 16 steps, B-ring 8) ----------
    {
      const __bf16* wbase = W2P + lq * 4096 + (w * 64 + lr) * 8;
      bfv8 Bb[8];
#pragma unroll
      for (int u = 0; u < 8; ++u)
        Bb[u] = *(const bfv8*)(wbase + (u & 15) * 16384 + (u >> 4) * 128);
      bfv8 A[16];
#pragma unroll
      for (int c = 0; c < 16; ++c)
        A[c] = *(const bfv8*)(h1c + lr * 1024 +
                              (((c * 64) + lq * 16) ^ ((lr & 7) << 4)));
      f32x4 Ca = splat4(0.f), Cb = splat4(0.f);
#pragma unroll
      for (int u = 0; u < 64; ++u) {
        const int c = u & 15, n = u >> 4;
        if (c == 0) { Ca = splat4(0.f); Cb = splat4(0.f); }
        if (u & 1)
          Cb = __builtin_amdgcn_mfma_f32_16x16x32_bf16(A[c], Bb[u & 7], Cb, 0, 0, 0);
        else
          Ca = __builtin_amdgcn_mfma_f32_16x16x32_bf16(A[c], Bb[u & 7], Ca, 0, 0, 0);
        if (u + 8 < 64)
          Bb[u & 7] = *(const bfv8*)(wbase + ((u + 8) & 15) * 16384 +
                                     ((u + 8) >> 4) * 128);
        if (c == 15) {
#pragma unroll
          for (int r = 0; r < 4; ++r) {
            const int row = lq * 4 + r;
            const int col = w * 64 + n * 16 + lr;
            const float tv = fast_tanh(Ca[r] + Cb[r] + b2c[n]);
            const int boff = row * 1024 + ((col * 2) ^ ((row & 7) << 4));
            *(__bf16*)((char*)h2s + boff) = (__bf16)tv;
            *(__bf16*)((char*)vs + boff) = (__bf16)(1.f - tv * tv);
          }
        }
      }
    }
    __syncthreads();  // bar2

    // ------- phase C: TR 64 half-chunks (waves 0-6: 9 each, wave 7: 1) ------
    //         + L3 full-K on wave 7 (plain kcur stores, no atomics)
    {
      const int nTR = (w < 7) ? 9 : 1;
      const int id0 = (w < 7) ? w * 9 : 63;
      float pacc[4] = {0.f, 0.f, 0.f, 0.f};
      bfv8 Bn[8], Bc[8];
      {
        const int tl = id0 >> 1, hf = id0 & 1;
        const __bf16* bp = GtP + (hf * 32 + lq) * 4096 + (tl * 16 + lr) * 8;
#pragma unroll
        for (int c = 0; c < 8; ++c) Bn[c] = *(const bfv8*)(bp + c * 16384);
      }
#pragma unroll
      for (int i = 0; i < 9; ++i) {
        if (i < nTR) {
          const int id = id0 + i;
          const int tl = id >> 1, hf = id & 1;
#pragma unroll
          for (int c = 0; c < 8; ++c) Bc[c] = Bn[c];
          if (i + 1 < nTR) {
            const int id2 = id + 1;
            const int tl2 = id2 >> 1, hf2 = id2 & 1;
            const __bf16* bp =
                GtP + (hf2 * 32 + lq) * 4096 + (tl2 * 16 + lr) * 8;
#pragma unroll
            for (int c = 0; c < 8; ++c) Bn[c] = *(const bfv8*)(bp + c * 16384);
          }
          bfv8 Ac[8];
#pragma unroll
          for (int c = 0; c < 8; ++c)
            Ac[c] = *(const bfv8*)(vsc + lr * 1024 +
                                   ((((hf * 8 + c) * 64) + lq * 16) ^
                                    ((lr & 7) << 4)));
          f32x4 C = splat4(0.f);
#pragma unroll
          for (int c = 0; c < 8; ++c)
            C = __builtin_amdgcn_mfma_f32_16x16x32_bf16(Ac[c], Bc[c], C, 0, 0, 0);
#pragma unroll
          for (int r = 0; r < 4; ++r) {
            const int row = lq * 4 + r;
            const float h1v = (float)*(const __bf16*)(
                h1c + row * 1024 + (((tl * 16 + lr) * 2) ^ ((row & 7) << 4)));
            pacc[r] += C[r] * (1.f - h1v * h1v);
          }
        }
      }
#pragma unroll
      for (int r = 0; r < 4; ++r) {
        float p = pacc[r];
        p += __shfl_xor(p, 1);
        p += __shfl_xor(p, 2);
        p += __shfl_xor(p, 4);
        p += __shfl_xor(p, 8);
        if (lr == 0) atomicAdd(&trbuf[lq * 4 + r], p);
      }
      if (w == 7) {  // L3: kcur = h2 @ W3 + b3, full K, 4 col-tiles
        bfv8 A2[16];
#pragma unroll
        for (int c = 0; c < 16; ++c)
          A2[c] = *(const bfv8*)(h2c + lr * 1024 +
                                 (((c * 64) + lq * 16) ^ ((lr & 7) << 4)));
#pragma unroll
        for (int tl = 0; tl < 4; ++tl) {
          f32x4 C = splat4(b3c[tl]);
#pragma unroll
          for (int c = 0; c < 16; ++c)
            C = __builtin_amdgcn_mfma_f32_16x16x32_bf16(
                A2[c], *(const bfv8*)(W3P + (4 * c + lq) * 512 +
                                      (tl * 16 + lr) * 8),
                C, 0, 0, 0);
#pragma unroll
          for (int r = 0; r < 4; ++r)
            kcur[(lq * 4 + r) * 64 + tl * 16 + lr] = C[r];
        }
      }
    }
    __syncthreads();  // bar3
  }

  // epilogue: final state -> out
  if (w == 0) {
    float* orow = out + (rowbase + lr) * 64 + lq * 8;
#pragma unroll
    for (int e = 0; e < 8; ++e) { orow[e] = xb0[e]; orow[32 + e] = xb1[e]; }
  }
  if (w == 7 && lq == 0) out[512 * 64 + rowbase + lr] = ldv;
}

extern "C" void kernel_launch(void* const* d_in, const int* in_sizes, int n_in,
                              void* d_out, int out_size, void* d_ws,
                              size_t ws_size, hipStream_t stream) {
  const float* x = (const float*)d_in[0];
  const float* W1 = (const float*)d_in[1];
  const float* b1 = (const float*)d_in[2];
  const float* W2 = (const float*)d_in[3];
  const float* b2 = (const float*)d_in[4];
  const float* W3 = (const float*)d_in[5];
  const float* b3 = (const float*)d_in[6];
  float* out = (float*)d_out;
  __bf16* wsb = (__bf16*)d_ws;

  __bf16* W1P = wsb;            // 32768
  __bf16* W2P = wsb + 32768;    // 262144
  __bf16* GtP = wsb + 294912;   // 262144
  __bf16* W3P = wsb + 557056;   // 32768

  pre_kernel<<<288, 256, 0, stream>>>(W1, W2, W3, W1P, W2P, GtP, W3P);
  cnf_kernel<<<32, 512, 0, stream>>>(x, W1, b1, b2, b3, W1P, W2P, GtP, W3P,
                                     out);
}

// Round 6
// 1300.992 us; speedup vs baseline: 1.6030x; 1.6030x over previous
//
#include <hip/hip_runtime.h>

#define NSTEPS 8
#define DT (1.0f / NSTEPS)

typedef __bf16 bfv8 __attribute__((ext_vector_type(8)));
typedef float f32x4 __attribute__((ext_vector_type(4)));

static __device__ __forceinline__ float fast_tanh(float x) {
  float e = __expf(2.f * x);
  return 1.f - 2.f * __builtin_amdgcn_rcpf(e + 1.f);
}

static __device__ __forceinline__ f32x4 splat4(float v) {
  f32x4 r; r[0] = v; r[1] = v; r[2] = v; r[3] = v; return r;
}

// ---------------------------------------------------------------------------
// Packed weight layouts (bf16), fragment-major for coalesced B-loads:
//  W1P[kq][512][8]  kq<8  : W1P[kq*4096+col*8+e] = W1[(kq*8+e)*512+col]
//  W2P[kc][512][8]  kc<64 : = W2[(kc*8+e)*512+col]
//  GtP[kc][512][8]  kc<64 : = G[j=col, k=kc*8+e],  G[j,k]=W2[j,k]*sum_i W1[i,j]W3[k,i]
//  W3P[kc][64][8]   kc<64 : = W3[(kc*8+e)*64+m]
// ---------------------------------------------------------------------------
__global__ __launch_bounds__(256) void pre_kernel(
    const float* __restrict__ W1, const float* __restrict__ W2,
    const float* __restrict__ W3, __bf16* __restrict__ W1P,
    __bf16* __restrict__ W2P, __bf16* __restrict__ GtP,
    __bf16* __restrict__ W3P) {
  int t = blockIdx.x * 256 + threadIdx.x;  // 73728 frags total
  if (t < 4096) {
    int kq = t >> 9, col = t & 511;
    bfv8 o;
#pragma unroll
    for (int e = 0; e < 8; ++e) o[e] = (__bf16)W1[(kq * 8 + e) * 512 + col];
    *(bfv8*)(W1P + t * 8) = o;
  } else if (t < 36864) {
    int g = t - 4096;
    int kc = g >> 9, col = g & 511;
    bfv8 o;
#pragma unroll
    for (int e = 0; e < 8; ++e) o[e] = (__bf16)W2[(kc * 8 + e) * 512 + col];
    *(bfv8*)(W2P + g * 8) = o;
  } else if (t < 69632) {
    int g = t - 36864;
    int kc = g >> 9, j = g & 511;
    float w1c[64];
#pragma unroll
    for (int m = 0; m < 64; ++m) w1c[m] = W1[m * 512 + j];
    bfv8 o;
#pragma unroll
    for (int e = 0; e < 8; ++e) {
      int k = kc * 8 + e;
      float s = 0.f;
#pragma unroll
      for (int m = 0; m < 64; ++m) s = fmaf(w1c[m], W3[k * 64 + m], s);
      o[e] = (__bf16)(s * W2[j * 512 + k]);
    }
    *(bfv8*)(GtP + g * 8) = o;
  } else if (t < 73728) {
    int g = t - 69632;
    int kc = g >> 6, m = g & 63;
    bfv8 o;
#pragma unroll
    for (int e = 0; e < 8; ++e) o[e] = (__bf16)W3[(kc * 8 + e) * 64 + m];
    *(bfv8*)(W3P + g * 8) = o;
  }
}

// ---------------------------------------------------------------------------
// Persistent integrator: 32 blocks x 16 rows, 16 waves (1024 thr), <=128 VGPR.
// MFMA 16x16x32 bf16 (m89 mapping): A row=lane&15, k=(lane>>4)*8+i;
// B col=lane&15, same k; D col=lane&15, row=(lane>>4)*4+reg.
// Per eval: combine(LDS) barA L1 barB L2 barC [TR w0-13 | L3 w14-15] barD
// ---------------------------------------------------------------------------
__global__ __launch_bounds__(1024, 4) void cnf_kernel(
    const float* __restrict__ x, const float* __restrict__ W1,
    const float* __restrict__ b1, const float* __restrict__ b2,
    const float* __restrict__ b3, const __bf16* __restrict__ W1P,
    const __bf16* __restrict__ W2P, const __bf16* __restrict__ GtP,
    const __bf16* __restrict__ W3P, float* __restrict__ out) {
  __shared__ __bf16 h1s[16 * 512];  // [row][col], byte ^= (row&7)<<4
  __shared__ __bf16 h2s[16 * 512];
  __shared__ __bf16 vs[16 * 512];
  __shared__ __bf16 xins[16 * 64];  // same swizzle, 128B rows
  __shared__ float xbs[1024];
  __shared__ float kacc[1024];
  __shared__ float kcur[1024];
  __shared__ float trbuf[16];
  __shared__ float ldvs[16];
  __shared__ float ldaccs[16];

  const int tid = threadIdx.x;
  const int lane = tid & 63;
  const int w = tid >> 6;    // 0..15
  const int lr = lane & 15;
  const int lq = lane >> 4;
  const int rowbase = blockIdx.x * 16;
  const char* h1c = (const char*)h1s;
  const char* h2c = (const char*)h2s;
  const char* vsc = (const char*)vs;

  // hoisted per-lane constants (2 col-tiles per wave in L1/L2)
  float b1c[2], w1tc[2], b2c[2];
#pragma unroll
  for (int n = 0; n < 2; ++n) {
    const int col = (w * 2 + n) * 16 + lr;
    b1c[n] = b1[col];
    w1tc[n] = W1[64 * 512 + col];
    b2c[n] = b2[col];
  }
  float b3c0 = 0.f, b3c1 = 0.f;
  if (w >= 14) {
    b3c0 = b3[((w - 14) * 2) * 16 + lr];
    b3c1 = b3[((w - 14) * 2 + 1) * 16 + lr];
  }

#pragma unroll 1
  for (int ev = 0; ev <= 4 * NSTEPS; ++ev) {
    // ---------------- combine (elementwise, state in LDS) ----------------
    {
      const int row = tid >> 6, cx = tid & 63;
      float xw;
      if (ev == 0) {
        xw = x[rowbase * 64 + tid];
        xbs[tid] = xw;
        kacc[tid] = 0.f;
        if (tid < 16) { trbuf[tid] = 0.f; ldvs[tid] = 0.f; ldaccs[tid] = 0.f; }
      } else {
        const int gp = (ev - 1) & 3;
        const float kv = kcur[tid];
        if (gp < 3) {
          kacc[tid] += ((gp == 0) ? 1.f : 2.f) * kv;
          xw = xbs[tid] + ((gp == 2) ? DT : 0.5f * DT) * kv;
        } else {
          xw = xbs[tid] + (DT / 6.f) * (kacc[tid] + kv);
          xbs[tid] = xw;
          kacc[tid] = 0.f;
        }
        if (tid < 16) {
          const float tv = trbuf[tid];
          trbuf[tid] = 0.f;
          if (gp < 3) {
            ldaccs[tid] += ((gp == 0) ? 1.f : 2.f) * tv;
          } else {
            const float lv = ldvs[tid] - (DT / 6.f) * (ldaccs[tid] + tv);
            ldvs[tid] = lv;
            ldaccs[tid] = 0.f;
            if (ev == 4 * NSTEPS) out[512 * 64 + rowbase + tid] = lv;
          }
        }
        if (ev == 4 * NSTEPS) out[rowbase * 64 + tid] = xw;
      }
      if (ev < 4 * NSTEPS)
        *(__bf16*)((char*)xins + row * 128 + ((cx * 2) ^ ((row & 7) << 4))) =
            (__bf16)xw;
    }
    if (ev == 4 * NSTEPS) break;
    __syncthreads();  // barA

    // ---------------- L1: h1 = tanh([xin,t] @ W1 + b1) ----------------
    {
      const int g = ev & 3;
      const float tval =
          (ev >> 2) * DT + ((g == 0) ? 0.f : (g == 3) ? DT : 0.5f * DT);
      bfv8 a0 = *(const bfv8*)((const char*)xins + lr * 128 +
                               ((lq * 16) ^ ((lr & 7) << 4)));
      bfv8 a1 = *(const bfv8*)((const char*)xins + lr * 128 +
                               ((64 + lq * 16) ^ ((lr & 7) << 4)));
#pragma unroll
      for (int n = 0; n < 2; ++n) {
        const int col = (w * 2 + n) * 16 + lr;
        f32x4 C = splat4(b1c[n] + tval * w1tc[n]);
        C = __builtin_amdgcn_mfma_f32_16x16x32_bf16(
            a0, *(const bfv8*)(W1P + lq * 4096 + col * 8), C, 0, 0, 0);
        C = __builtin_amdgcn_mfma_f32_16x16x32_bf16(
            a1, *(const bfv8*)(W1P + (lq + 4) * 4096 + col * 8), C, 0, 0, 0);
#pragma unroll
        for (int r = 0; r < 4; ++r) {
          const int row = lq * 4 + r;
          *(__bf16*)((char*)h1s + row * 1024 +
                     ((col * 2) ^ ((row & 7) << 4))) = (__bf16)fast_tanh(C[r]);
        }
      }
    }
    __syncthreads();  // barB

    // ---------------- L2: h2 = tanh(h1 @ W2 + b2); v = 1-h2^2 ----------
    {
      const int c0 = (w * 2) * 16 + lr, c1 = (w * 2 + 1) * 16 + lr;
      f32x4 C0 = splat4(0.f), C1 = splat4(0.f);
#pragma unroll
      for (int c = 0; c < 16; ++c) {
        bfv8 A = *(const bfv8*)(h1c + lr * 1024 +
                                (((c * 64) + lq * 16) ^ ((lr & 7) << 4)));
        C0 = __builtin_amdgcn_mfma_f32_16x16x32_bf16(
            A, *(const bfv8*)(W2P + (4 * c + lq) * 4096 + c0 * 8), C0, 0, 0, 0);
        C1 = __builtin_amdgcn_mfma_f32_16x16x32_bf16(
            A, *(const bfv8*)(W2P + (4 * c + lq) * 4096 + c1 * 8), C1, 0, 0, 0);
      }
#pragma unroll
      for (int r = 0; r < 4; ++r) {
        const int row = lq * 4 + r;
        const float t0 = fast_tanh(C0[r] + b2c[0]);
        const float t1 = fast_tanh(C1[r] + b2c[1]);
        const int bo0 = row * 1024 + ((c0 * 2) ^ ((row & 7) << 4));
        const int bo1 = row * 1024 + ((c1 * 2) ^ ((row & 7) << 4));
        *(__bf16*)((char*)h2s + bo0) = (__bf16)t0;
        *(__bf16*)((char*)vs + bo0) = (__bf16)(1.f - t0 * t0);
        *(__bf16*)((char*)h2s + bo1) = (__bf16)t1;
        *(__bf16*)((char*)vs + bo1) = (__bf16)(1.f - t1 * t1);
      }
    }
    __syncthreads();  // barC

    // ---- phase C: TR 64 half-units on waves 0-13; L3 on waves 14-15 ----
    if (w < 14) {
      const int nU = (w < 8) ? 5 : 4;
      const int base = (w < 8) ? w * 5 : 40 + (w - 8) * 4;
      float pacc[4] = {0.f, 0.f, 0.f, 0.f};
#pragma unroll
      for (int i = 0; i < 5; ++i) {
        if (i < nU) {
          const int id = base + i;
          const int tl = id >> 1, hf = id & 1;  // j-tile, K-half
          const __bf16* bp =
              GtP + (hf * 32 + lq) * 4096 + (tl * 16 + lr) * 8;
          f32x4 C = splat4(0.f);
#pragma unroll
          for (int c = 0; c < 8; ++c) {
            bfv8 Ac = *(const bfv8*)(vsc + lr * 1024 +
                                     ((((hf * 8 + c) * 64) + lq * 16) ^
                                      ((lr & 7) << 4)));
            C = __builtin_amdgcn_mfma_f32_16x16x32_bf16(
                Ac, *(const bfv8*)(bp + c * 16384), C, 0, 0, 0);
          }
#pragma unroll
          for (int r = 0; r < 4; ++r) {
            const int row = lq * 4 + r;
            const float h1v = (float)*(const __bf16*)(
                h1c + row * 1024 + (((tl * 16 + lr) * 2) ^ ((row & 7) << 4)));
            pacc[r] += C[r] * (1.f - h1v * h1v);
          }
        }
      }
#pragma unroll
      for (int r = 0; r < 4; ++r) {
        float p = pacc[r];
        p += __shfl_xor(p, 1);
        p += __shfl_xor(p, 2);
        p += __shfl_xor(p, 4);
        p += __shfl_xor(p, 8);
        if (lr == 0) atomicAdd(&trbuf[lq * 4 + r], p);
      }
    } else {
      // L3: kcur = h2 @ W3 + b3; wave 14 -> tiles 0,1; wave 15 -> 2,3
      const int tla = (w - 14) * 2, tlb = tla + 1;
      f32x4 Ca = splat4(b3c0), Cb = splat4(b3c1);
#pragma unroll
      for (int c = 0; c < 16; ++c) {
        bfv8 A = *(const bfv8*)(h2c + lr * 1024 +
                                (((c * 64) + lq * 16) ^ ((lr & 7) << 4)));
        Ca = __builtin_amdgcn_mfma_f32_16x16x32_bf16(
            A, *(const bfv8*)(W3P + (4 * c + lq) * 512 + (tla * 16 + lr) * 8),
            Ca, 0, 0, 0);
        Cb = __builtin_amdgcn_mfma_f32_16x16x32_bf16(
            A, *(const bfv8*)(W3P + (4 * c + lq) * 512 + (tlb * 16 + lr) * 8),
            Cb, 0, 0, 0);
      }
#pragma unroll
      for (int r = 0; r < 4; ++r) {
        kcur[(lq * 4 + r) * 64 + tla * 16 + lr] = Ca[r];
        kcur[(lq * 4 + r) * 64 + tlb * 16 + lr] = Cb[r];
      }
    }
    __syncthreads();  // barD
  }
}

extern "C" void kernel_launch(void* const* d_in, const int* in_sizes, int n_in,
                              void* d_out, int out_size, void* d_ws,
                              size_t ws_size, hipStream_t stream) {
  const float* x = (const float*)d_in[0];
  const float* W1 = (const float*)d_in[1];
  const float* b1 = (const float*)d_in[2];
  const float* W2 = (const float*)d_in[3];
  const float* b2 = (const float*)d_in[4];
  const float* W3 = (const float*)d_in[5];
  const float* b3 = (const float*)d_in[6];
  float* out = (float*)d_out;
  __bf16* wsb = (__bf16*)d_ws;

  __bf16* W1P = wsb;            // 32768 elems
  __bf16* W2P = wsb + 32768;    // 262144
  __bf16* GtP = wsb + 294912;   // 262144
  __bf16* W3P = wsb + 557056;   // 32768

  pre_kernel<<<288, 256, 0, stream>>>(W1, W2, W3, W1P, W2P, GtP, W3P);
  cnf_kernel<<<32, 1024, 0, stream>>>(x, W1, b1, b2, b3, W1P, W2P, GtP, W3P,
                                      out);
}

// Round 7
// 1085.292 us; speedup vs baseline: 1.9216x; 1.1987x over previous
//
#include <hip/hip_runtime.h>

#define NSTEPS 8
#define DT (1.0f / NSTEPS)

typedef __bf16 bfv8 __attribute__((ext_vector_type(8)));
typedef float f32x4 __attribute__((ext_vector_type(4)));

static __device__ __forceinline__ float fast_tanh(float x) {
  float e = __expf(2.f * x);
  return 1.f - 2.f * __builtin_amdgcn_rcpf(e + 1.f);
}

static __device__ __forceinline__ f32x4 splat4(float v) {
  f32x4 r; r[0] = v; r[1] = v; r[2] = v; r[3] = v; return r;
}

// ---------------------------------------------------------------------------
// Packed weight layouts (bf16), fragment-major for coalesced B-loads:
//  W1P[kq][512][8]  kq<8  : W1P[kq*4096+col*8+e] = W1[(kq*8+e)*512+col]
//  W2P[kc][512][8]  kc<64 : = W2[(kc*8+e)*512+col]
//  GtP[kc][512][8]  kc<64 : = G[j=col, k=kc*8+e],  G[j,k]=W2[j,k]*sum_i W1[i,j]W3[k,i]
//  W3P[kc][64][8]   kc<64 : = W3[(kc*8+e)*64+m]
// ---------------------------------------------------------------------------
__global__ __launch_bounds__(256) void pre_kernel(
    const float* __restrict__ W1, const float* __restrict__ W2,
    const float* __restrict__ W3, __bf16* __restrict__ W1P,
    __bf16* __restrict__ W2P, __bf16* __restrict__ GtP,
    __bf16* __restrict__ W3P) {
  int t = blockIdx.x * 256 + threadIdx.x;  // 73728 frags total
  if (t < 4096) {
    int kq = t >> 9, col = t & 511;
    bfv8 o;
#pragma unroll
    for (int e = 0; e < 8; ++e) o[e] = (__bf16)W1[(kq * 8 + e) * 512 + col];
    *(bfv8*)(W1P + t * 8) = o;
  } else if (t < 36864) {
    int g = t - 4096;
    int kc = g >> 9, col = g & 511;
    bfv8 o;
#pragma unroll
    for (int e = 0; e < 8; ++e) o[e] = (__bf16)W2[(kc * 8 + e) * 512 + col];
    *(bfv8*)(W2P + g * 8) = o;
  } else if (t < 69632) {
    int g = t - 36864;
    int kc = g >> 9, j = g & 511;
    float w1c[64];
#pragma unroll
    for (int m = 0; m < 64; ++m) w1c[m] = W1[m * 512 + j];
    bfv8 o;
#pragma unroll
    for (int e = 0; e < 8; ++e) {
      int k = kc * 8 + e;
      float s = 0.f;
#pragma unroll
      for (int m = 0; m < 64; ++m) s = fmaf(w1c[m], W3[k * 64 + m], s);
      o[e] = (__bf16)(s * W2[j * 512 + k]);
    }
    *(bfv8*)(GtP + g * 8) = o;
  } else if (t < 73728) {
    int g = t - 69632;
    int kc = g >> 6, m = g & 63;
    bfv8 o;
#pragma unroll
    for (int e = 0; e < 8; ++e) o[e] = (__bf16)W3[(kc * 8 + e) * 64 + m];
    *(bfv8*)(W3P + g * 8) = o;
  }
}

// ---------------------------------------------------------------------------
// Persistent integrator: 32 blocks x 16 rows, 8 waves, 4-deep reg-ring streams.
// MFMA 16x16x32 bf16 (m89 mapping): A row=lane&15, k=(lane>>4)*8+i;
// B col=lane&15, same k; D col=lane&15, row=(lane>>4)*4+reg.
// Per eval: combine(reg) bar L1 bar L2 bar [TR ; L3(k-split all waves)] bar
// ---------------------------------------------------------------------------
__global__ __launch_bounds__(512, 2) void cnf_kernel(
    const float* __restrict__ x, const float* __restrict__ b1,
    const float* __restrict__ W1, const float* __restrict__ b2,
    const float* __restrict__ b3, const __bf16* __restrict__ W1P,
    const __bf16* __restrict__ W2P, const __bf16* __restrict__ GtP,
    const __bf16* __restrict__ W3P, float* __restrict__ out) {
  __shared__ __bf16 h1s[8192];  // [row][col] bytes, byte ^= (row&7)<<4
  __shared__ __bf16 h2s[8192];
  __shared__ __bf16 vs[8192];
  __shared__ __bf16 xins[1024];  // [16][64] plain
  __shared__ float kcur[1024];
  __shared__ float trbuf[16];

  const int tid = threadIdx.x;
  const int lane = tid & 63;
  const int w = tid >> 6;    // 0..7
  const int lr = lane & 15;
  const int lq = lane >> 4;
  const int rowbase = blockIdx.x * 16;
  const char* h1c = (const char*)h1s;
  const char* h2c = (const char*)h2s;
  const char* vsc = (const char*)vs;

  // hoisted per-lane constants (4 col-tiles per wave)
  float b1c[4], w1tc[4], b2c[4], b3c[4];
#pragma unroll
  for (int n = 0; n < 4; ++n) {
    const int col = (w * 4 + n) * 16 + lr;
    b1c[n] = b1[col];
    w1tc[n] = W1[64 * 512 + col];
    b2c[n] = b2[col];
    b3c[n] = b3[n * 16 + lr];
  }

  // per-thread RK4 state: elements tid and tid+512 of [16 rows][64]
  float xbA = 0.f, xbB = 0.f, kaA = 0.f, kaB = 0.f, ldv = 0.f, ldacc = 0.f;

#pragma unroll 1
  for (int ev = 0; ev <= 4 * NSTEPS; ++ev) {
    const int g = ev & 3;
    // ---------------- combine (per-thread registers) ----------------
    {
      float xwA, xwB;
      if (ev == 0) {
        xbA = x[rowbase * 64 + tid];
        xbB = x[rowbase * 64 + 512 + tid];
        xwA = xbA; xwB = xbB;
        kcur[tid] = 0.f; kcur[tid + 512] = 0.f;
        if (tid < 16) trbuf[tid] = 0.f;
      } else {
        const int gp = (ev - 1) & 3;
        const float k0 = kcur[tid], k1 = kcur[tid + 512];
        kcur[tid] = 0.f; kcur[tid + 512] = 0.f;
        float tv = 0.f;
        if (tid < 16) { tv = trbuf[tid]; trbuf[tid] = 0.f; }
        if (gp < 3) {
          const float wg = (gp == 0) ? 1.f : 2.f;
          const float cn = (gp == 2) ? DT : 0.5f * DT;
          kaA += wg * k0; kaB += wg * k1;
          xwA = xbA + cn * k0; xwB = xbB + cn * k1;
          if (tid < 16) ldacc += wg * tv;
        } else {
          xbA += (DT / 6.f) * (kaA + k0);
          xbB += (DT / 6.f) * (kaB + k1);
          kaA = 0.f; kaB = 0.f;
          xwA = xbA; xwB = xbB;
          if (tid < 16) { ldv -= (DT / 6.f) * (ldacc + tv); ldacc = 0.f; }
        }
      }
      if (ev == 4 * NSTEPS) {
        out[rowbase * 64 + tid] = xwA;
        out[rowbase * 64 + 512 + tid] = xwB;
        if (tid < 16) out[512 * 64 + rowbase + tid] = ldv;
        break;
      }
      xins[tid] = (__bf16)xwA;
      xins[tid + 512] = (__bf16)xwB;
    }
    __syncthreads();  // bar1

    // ---------------- L1: h1 = tanh([xin,t] @ W1 + b1) ----------------
    {
      const float tval =
          (ev >> 2) * DT + ((g == 0) ? 0.f : (g == 3) ? DT : 0.5f * DT);
      const bfv8 a0 = *(const bfv8*)&xins[lr * 64 + lq * 8];
      const bfv8 a1 = *(const bfv8*)&xins[lr * 64 + 32 + lq * 8];
      bfv8 ring[4];
#pragma unroll
      for (int p = 0; p < 4; ++p)
        ring[p] = *(const bfv8*)(W1P + ((p & 1) * 4 + lq) * 4096 +
                                 ((w * 4 + (p >> 1)) * 16 + lr) * 8);
      f32x4 C = splat4(0.f);
#pragma unroll
      for (int f = 0; f < 8; ++f) {
        const int n = f >> 1, h = f & 1;
        if (h == 0) C = splat4(b1c[n] + tval * w1tc[n]);
        C = __builtin_amdgcn_mfma_f32_16x16x32_bf16(h ? a1 : a0, ring[f & 3],
                                                    C, 0, 0, 0);
        if (f < 4) {
          const int f4 = f + 4;
          ring[f & 3] = *(const bfv8*)(W1P + ((f4 & 1) * 4 + lq) * 4096 +
                                       ((w * 4 + (f4 >> 1)) * 16 + lr) * 8);
        }
        if (h == 1) {
#pragma unroll
          for (int r = 0; r < 4; ++r) {
            const int row = lq * 4 + r;
            const int col = (w * 4 + n) * 16 + lr;
            *(__bf16*)((char*)h1s + row * 1024 +
                       ((col * 2) ^ ((row & 7) << 4))) = (__bf16)fast_tanh(C[r]);
          }
        }
      }
    }
    __syncthreads();  // bar2

    // ---------------- L2: h2 = tanh(h1 @ W2 + b2); v = 1-h2^2 ----------
    {
      bfv8 A[16];
#pragma unroll
      for (int c = 0; c < 16; ++c)
        A[c] = *(const bfv8*)(h1c + lr * 1024 +
                              (((c * 64) + lq * 16) ^ ((lr & 7) << 4)));
      bfv8 ring[4];
#pragma unroll
      for (int p = 0; p < 4; ++p)
        ring[p] = *(const bfv8*)(W2P + (p * 4 + lq) * 4096 +
                                 ((w * 4) * 16 + lr) * 8);
      f32x4 C = splat4(0.f);
#pragma unroll
      for (int f = 0; f < 64; ++f) {
        const int c = f & 15, t = f >> 4;
        if (c == 0) C = splat4(0.f);
        C = __builtin_amdgcn_mfma_f32_16x16x32_bf16(A[c], ring[f & 3], C, 0, 0,
                                                    0);
        if (f < 60) {
          const int f4 = f + 4;
          ring[f & 3] = *(const bfv8*)(W2P + ((f4 & 15) * 4 + lq) * 4096 +
                                       ((w * 4 + (f4 >> 4)) * 16 + lr) * 8);
        }
        if (c == 15) {
#pragma unroll
          for (int r = 0; r < 4; ++r) {
            const int row = lq * 4 + r;
            const int col = (w * 4 + t) * 16 + lr;
            const float tv = fast_tanh(C[r] + b2c[t]);
            const int bo = row * 1024 + ((col * 2) ^ ((row & 7) << 4));
            *(__bf16*)((char*)h2s + bo) = (__bf16)tv;
            *(__bf16*)((char*)vs + bo) = (__bf16)(1.f - tv * tv);
          }
        }
      }
    }
    __syncthreads();  // bar3

    // ------- TR: y = v @ G^T per j-tile; tr += sum_j u*y  (reg ring) -------
    {
      bfv8 A[16];
#pragma unroll
      for (int c = 0; c < 16; ++c)
        A[c] = *(const bfv8*)(vsc + lr * 1024 +
                              (((c * 64) + lq * 16) ^ ((lr & 7) << 4)));
      bfv8 ring[4];
#pragma unroll
      for (int p = 0; p < 4; ++p)
        ring[p] = *(const bfv8*)(GtP + (p * 4 + lq) * 4096 +
                                 ((w * 4) * 16 + lr) * 8);
      f32x4 C = splat4(0.f);
      float pacc[4] = {0.f, 0.f, 0.f, 0.f};
#pragma unroll
      for (int f = 0; f < 64; ++f) {
        const int c = f & 15, t = f >> 4;
        if (c == 0) C = splat4(0.f);
        C = __builtin_amdgcn_mfma_f32_16x16x32_bf16(A[c], ring[f & 3], C, 0, 0,
                                                    0);
        if (f < 60) {
          const int f4 = f + 4;
          ring[f & 3] = *(const bfv8*)(GtP + ((f4 & 15) * 4 + lq) * 4096 +
                                       ((w * 4 + (f4 >> 4)) * 16 + lr) * 8);
        }
        if (c == 15) {
#pragma unroll
          for (int r = 0; r < 4; ++r) {
            const int row = lq * 4 + r;
            const int col = (w * 4 + t) * 16 + lr;
            const float h1v = (float)*(const __bf16*)(
                h1c + row * 1024 + ((col * 2) ^ ((row & 7) << 4)));
            pacc[r] += C[r] * (1.f - h1v * h1v);
          }
        }
      }
#pragma unroll
      for (int r = 0; r < 4; ++r) {
        float p = pacc[r];
        p += __shfl_xor(p, 1);
        p += __shfl_xor(p, 2);
        p += __shfl_xor(p, 4);
        p += __shfl_xor(p, 8);
        if (lr == 0) atomicAdd(&trbuf[lq * 4 + r], p);
      }
    }

    // ------- L3 (k-split across all 8 waves): kcur += h2[:,wk] @ W3[wk,:] ---
    {
      bfv8 A2[2];
#pragma unroll
      for (int h = 0; h < 2; ++h)
        A2[h] = *(const bfv8*)(h2c + lr * 1024 +
                               (((w * 128 + h * 64 + lq * 16)) ^
                                ((lr & 7) << 4)));
      bfv8 ring[4];
#pragma unroll
      for (int p = 0; p < 4; ++p)
        ring[p] = *(const bfv8*)(W3P + (w * 8 + (p & 1) * 4 + lq) * 512 +
                                 ((p >> 1) * 16 + lr) * 8);
      f32x4 C = splat4(0.f);
#pragma unroll
      for (int f = 0; f < 8; ++f) {
        const int mt = f >> 1, h = f & 1;
        if (h == 0) C = splat4((w == 0) ? b3c[mt] : 0.f);
        C = __builtin_amdgcn_mfma_f32_16x16x32_bf16(A2[h], ring[f & 3], C, 0,
                                                    0, 0);
        if (f < 4) {
          const int f4 = f + 4;
          ring[f & 3] =
              *(const bfv8*)(W3P + (w * 8 + (f4 & 1) * 4 + lq) * 512 +
                             ((f4 >> 1) * 16 + lr) * 8);
        }
        if (h == 1) {
#pragma unroll
          for (int r = 0; r < 4; ++r)
            atomicAdd(&kcur[(lq * 4 + r) * 64 + mt * 16 + lr], C[r]);
        }
      }
    }
    __syncthreads();  // bar4
  }
}

extern "C" void kernel_launch(void* const* d_in, const int* in_sizes, int n_in,
                              void* d_out, int out_size, void* d_ws,
                              size_t ws_size, hipStream_t stream) {
  const float* x = (const float*)d_in[0];
  const float* W1 = (const float*)d_in[1];
  const float* b1 = (const float*)d_in[2];
  const float* W2 = (const float*)d_in[3];
  const float* b2 = (const float*)d_in[4];
  const float* W3 = (const float*)d_in[5];
  const float* b3 = (const float*)d_in[6];
  float* out = (float*)d_out;
  __bf16* wsb = (__bf16*)d_ws;

  __bf16* W1P = wsb;            // 32768 elems
  __bf16* W2P = wsb + 32768;    // 262144
  __bf16* GtP = wsb + 294912;   // 262144
  __bf16* W3P = wsb + 557056;   // 32768

  pre_kernel<<<288, 256, 0, stream>>>(W1, W2, W3, W1P, W2P, GtP, W3P);
  cnf_kernel<<<32, 512, 0, stream>>>(x, b1, W1, b2, b3, W1P, W2P, GtP, W3P,
                                     out);
}